// Round 12
// baseline (190.925 us; speedup 1.0000x reference)
//
#include <hip/hip_runtime.h>
#include <cfloat>
#include <cmath>

#define NP 10000
#define NG 1000
#define NC 80
#define LMAX 6
#define NCH 4
#define CHSZ (NP / NCH)     // 2500 preds per wave-task (redo path)
#define WMAIN 39            // 39*64 = 2496
#define WTAIL 4             // + 4 = 2500

#define RI_BIG  0x3fffffff
#define KMAX    0xFFFFFFFFFFFFFFFFull

// packkey(50.0f,0): strong (inb) costs < ~28, non-strong >= ~59. Block-scope
// gate (proven R9/R11): if the gt's merged 5th-smallest key >= TKEY -> exact
// full rescan (all 10000 preds).
#define TKEY    0xC248000000000000ull

// spatial grid: 16 x 10 cells over the image; preds binned by center.
#define GX 16
#define GY 10
#define NCELL (GX * GY)

// prior-row cost cache: slots x 1000 floats (prior rows <= 2500)
#define PSLOTS  2560
#define PCAP    2560
#define FCAP    1024

__device__ __forceinline__ bool lexless(float av, int ai, float bv, int bi) {
    return (av < bv) || (av == bv && ai < bi);
}

// float -> order-preserving u32 (no NaNs in this data), packed with index.
__device__ __forceinline__ unsigned long long packkey(float v, int idx) {
    unsigned u = __float_as_uint(v);
    u ^= (unsigned)(((int)u) >> 31) | 0x80000000u;
    return ((unsigned long long)u << 32) | (unsigned)idx;
}
__device__ __forceinline__ int keyidx(unsigned long long k) {
    return (int)(unsigned)(k & 0xFFFFFFFFu);
}

// Exact sequential +1e5 inflation (reference adds 1e5 once per loop iter).
__device__ __forceinline__ float inflate(float c, int k) {
    for (int q = 0; q < k; q++) c += 100000.0f;
    return c;
}

// Per-pair cost+iou from precomputed tables. Contraction OFF so every kernel
// that recomputes cost(i,j) agrees bit-exactly.
__device__ __forceinline__ void cost_iou(float4 p, float4 pn, float4 pi,
        float4 g, float4 cb, float4 Gn, float ga, float clsv,
        float& cc_out, float& iou_out) {
#pragma clang fp contract(off)
    float wx = fminf(p.z, g.z) - fmaxf(p.x, g.x); wx = fmaxf(wx, 0.0f);
    float wy = fminf(p.w, g.w) - fmaxf(p.y, g.y); wy = fmaxf(wy, 0.0f);
    float inter = wx * wy;
    float uni = pi.z + ga - inter;
    float iou = inter / fmaxf(uni, 1e-12f);
    float ex = fmaxf(p.z, g.z) - fminf(p.x, g.x); ex = fmaxf(ex, 0.0f);
    float ey = fmaxf(p.w, g.w) - fminf(p.y, g.y); ey = fmaxf(ey, 0.0f);
    float enc = ex * ey;
    float giou = iou - (enc - uni) / fmaxf(enc, 1e-12f);
    float l1 = ((fabsf(pn.x - Gn.x) + fabsf(pn.y - Gn.y))
                + fabsf(pn.z - Gn.z)) + fabsf(pn.w - Gn.w);
    float cc = clsv + l1 * 5.0f;
    cc = cc + (-giou * 2.0f);
    bool inb = (pi.x > g.x && pi.x < g.z && pi.y > g.y && pi.y < g.w);
    bool inc = (pi.x > cb.x && pi.x < cb.z && pi.y > cb.y && pi.y < cb.w);
    cc = cc + ((inb && inc) ? 0.0f : 100.0f);
    cc = cc + pi.w;
    cc_out = cc; iou_out = iou;
}

// Proven per-lane sorted top-5 insertion (static indices after unroll).
__device__ __forceinline__ void ins5k(unsigned long long* kv,
        unsigned long long key) {
    if (key < kv[4]) {
        kv[4] = key;
#pragma unroll
        for (int t = 4; t > 0; t--)
            if (kv[t] < kv[t-1]) { unsigned long long tv = kv[t]; kv[t] = kv[t-1]; kv[t-1] = tv; }
    }
}
__device__ __forceinline__ void ins5i(float* iv, float iou) {
    if (iou > iv[4]) {
        iv[4] = iou;
#pragma unroll
        for (int t = 4; t > 0; t--)
            if (iv[t] > iv[t-1]) { float tv = iv[t]; iv[t] = iv[t-1]; iv[t-1] = tv; }
    }
}

// static 9-comparator sorting networks for 5 elements (constant indices only)
__device__ __forceinline__ void cswapk(unsigned long long& a,
        unsigned long long& b) {
    unsigned long long lo = (a < b) ? a : b;
    unsigned long long hi = (a < b) ? b : a;
    a = lo; b = hi;
}
__device__ __forceinline__ void sort5k(unsigned long long* a) {   // ascending
    cswapk(a[0],a[1]); cswapk(a[3],a[4]); cswapk(a[2],a[4]);
    cswapk(a[2],a[3]); cswapk(a[1],a[4]); cswapk(a[0],a[3]);
    cswapk(a[0],a[2]); cswapk(a[1],a[3]); cswapk(a[1],a[2]);
}
__device__ __forceinline__ void cswapi(float& a, float& b) {      // a=max
    float hi = fmaxf(a, b), lo = fminf(a, b);
    a = hi; b = lo;
}
__device__ __forceinline__ void sort5i(float* a) {                // descending
    cswapi(a[0],a[1]); cswapi(a[3],a[4]); cswapi(a[2],a[4]);
    cswapi(a[2],a[3]); cswapi(a[1],a[4]); cswapi(a[0],a[3]);
    cswapi(a[0],a[2]); cswapi(a[1],a[3]); cswapi(a[1],a[2]);
}

// 6-round butterfly allreduce of sorted 5-lists across the 64-lane wave
// (proven R8/R9/R11 on hardware).
__device__ __forceinline__ void wavemerge5(unsigned long long* kv, float* iv) {
#pragma unroll
    for (int d = 1; d < 64; d <<= 1) {
        unsigned long long r0 = __shfl_xor(kv[0], d);
        unsigned long long r1 = __shfl_xor(kv[1], d);
        unsigned long long r2 = __shfl_xor(kv[2], d);
        unsigned long long r3 = __shfl_xor(kv[3], d);
        unsigned long long r4 = __shfl_xor(kv[4], d);
        kv[0] = (kv[0] < r4) ? kv[0] : r4;
        kv[1] = (kv[1] < r3) ? kv[1] : r3;
        kv[2] = (kv[2] < r2) ? kv[2] : r2;
        kv[3] = (kv[3] < r1) ? kv[3] : r1;
        kv[4] = (kv[4] < r0) ? kv[4] : r0;
        sort5k(kv);
        float s0 = __shfl_xor(iv[0], d);
        float s1 = __shfl_xor(iv[1], d);
        float s2 = __shfl_xor(iv[2], d);
        float s3 = __shfl_xor(iv[3], d);
        float s4 = __shfl_xor(iv[4], d);
        iv[0] = fmaxf(iv[0], s4);
        iv[1] = fmaxf(iv[1], s3);
        iv[2] = fmaxf(iv[2], s2);
        iv[3] = fmaxf(iv[3], s1);
        iv[4] = fmaxf(iv[4], s0);
        sort5i(iv);
    }
}

// butterfly allreduce of lexless-argmin (val asc, idx asc) across a wave
__device__ __forceinline__ void wavered_lex(float& best, int& bi) {
#pragma unroll
    for (int d = 1; d < 64; d <<= 1) {
        float ov = __shfl_xor(best, d);
        int oi = __shfl_xor(bi, d);
        if (lexless(ov, oi, best, bi)) { best = ov; bi = oi; }
    }
}

// ---------------------------------------------------------------------------
// Fused prep (R11 + spatial-grid build). Block ranges:
//  [0,40): init state; [40,197): cls table; [197,201): per-gt tables;
//  [201,2701): wave-per-pred validity + per-pred tables;
//  2701: label counting-sort -> gorder (XCD clustering, proven R11);
//  2702: SPATIAL GRID build (single block): bin pred centers into 16x10
//        cells (count + prefix + scatter -> iorig, cellstart) and compute
//        hwmax (max pred half-extent) via block-local reduction — the cell
//        coverage radius used by k_cost2 (measured, not assumed).
// ---------------------------------------------------------------------------
#define CLS_TI 64
#define PB_CLS0 40
#define PB_G0   197
#define PB_V0   201
#define PB_SORT 2701
#define PB_GRID 2702
__global__ __launch_bounds__(256) void k_prep(const float* __restrict__ logits,
        const float* __restrict__ pb, const float* __restrict__ gb,
        const int* __restrict__ glab,
        const int* __restrict__ imgw, const int* __restrict__ imgh,
        float* __restrict__ clsval, float4* __restrict__ pnorm,
        float4* __restrict__ pinfo, float4* __restrict__ gcb,
        float4* __restrict__ gnm, float* __restrict__ gar,
        int* rowcnt, int* rowfirst, int* rowiter, int* prior, int* priorcol,
        int* colsum, int* scal, int* priorslot, int* gorder,
        int* __restrict__ iorig, int* __restrict__ cellstart,
        float* __restrict__ gridp)
{
    __shared__ float sl[CLS_TI * (NC + 1)];
    int b = blockIdx.x;
    if (b == PB_GRID) {
        __shared__ int hist[NCELL];
        __shared__ int basec[NCELL];
        __shared__ float shw[256];
        int tid = threadIdx.x;
        float cw = (float)imgw[0] / (float)GX;
        float ch = (float)imgh[0] / (float)GY;
        for (int c = tid; c < NCELL; c += 256) hist[c] = 0;
        __syncthreads();
        float hwm = 0.0f;
        const float4* pb4 = (const float4*)pb;
        for (int i = tid; i < NP; i += 256) {
            float4 p = pb4[i];
            float pcx = (p.x + p.z) * 0.5f, pcy = (p.y + p.w) * 0.5f;
            hwm = fmaxf(hwm, fmaxf((p.z - p.x) * 0.5f, (p.w - p.y) * 0.5f));
            int cx = (int)(pcx / cw); cx = min(max(cx, 0), GX - 1);
            int cy = (int)(pcy / ch); cy = min(max(cy, 0), GY - 1);
            atomicAdd(&hist[cy * GX + cx], 1);
        }
        shw[tid] = hwm;
        __syncthreads();
        for (int w = 128; w > 0; w >>= 1) {
            if (tid < w) shw[tid] = fmaxf(shw[tid], shw[tid + w]);
            __syncthreads();
        }
        if (tid == 0) {
            gridp[0] = shw[0];
            gridp[1] = cw;
            gridp[2] = ch;
            int acc = 0;
            for (int c = 0; c < NCELL; c++) {
                cellstart[c] = acc; basec[c] = acc; acc += hist[c];
            }
            cellstart[NCELL] = acc;     // == NP
        }
        __syncthreads();
        for (int i = tid; i < NP; i += 256) {
            float4 p = pb4[i];
            float pcx = (p.x + p.z) * 0.5f, pcy = (p.y + p.w) * 0.5f;
            int cx = (int)(pcx / cw); cx = min(max(cx, 0), GX - 1);
            int cy = (int)(pcy / ch); cy = min(max(cy, 0), GY - 1);
            int pos = atomicAdd(&basec[cy * GX + cx], 1);
            iorig[pos] = i;
        }
        return;
    }
    if (b == PB_SORT) {
        __shared__ int hist[NC];
        __shared__ int basec[NC];
        int tid = threadIdx.x;
        if (tid < NC) hist[tid] = 0;
        __syncthreads();
        for (int j = tid; j < NG; j += 256) atomicAdd(&hist[glab[j]], 1);
        __syncthreads();
        if (tid == 0) {
            int acc = 0;
            for (int c = 0; c < NC; c++) { basec[c] = acc; acc += hist[c]; }
        }
        __syncthreads();
        for (int j = tid; j < NG; j += 256) {
            int pos = atomicAdd(&basec[glab[j]], 1);
            gorder[pos] = j;
        }
        return;
    }
    if (b < PB_CLS0) {
        int i = b * 256 + threadIdx.x;
        if (i < NP) {
            rowcnt[i] = 0; rowfirst[i] = 0x7fffffff; rowiter[i] = RI_BIG;
            prior[i] = 0; priorcol[i] = 0; priorslot[i] = -1;
        }
        if (i < NG) colsum[i] = 0;
        if (i < 32) scal[i] = 0;
    } else if (b < PB_G0) {
        int i0 = (b - PB_CLS0) * CLS_TI;
        bool full = (i0 + CLS_TI) <= NP;
        if (full) {
            const float* src = logits + (size_t)i0 * NC;
            for (int e = threadIdx.x; e < CLS_TI * NC; e += 256) {
                int di = e / NC, c = e - di * NC;
                sl[di * (NC + 1) + c] = src[e];
            }
        } else {
            for (int e = threadIdx.x; e < CLS_TI * NC; e += 256) {
                int di = e / NC, c = e - di * NC;
                int i = i0 + di;
                sl[di * (NC + 1) + c] = (i < NP) ? logits[(size_t)i * NC + c] : 0.0f;
            }
        }
        __syncthreads();
        for (int e = threadIdx.x; e < CLS_TI * NC; e += 256) {
            int c = e >> 6, di = e & 63;
            int i = i0 + di;
            if (i >= NP) continue;
            float x = sl[di * (NC + 1) + c];
            float p = 1.0f / (1.0f + expf(-x));
            float neg = -log1pf(-(p - 1e-12f)) * 0.75f * (p * p);
            float om = 1.0f - p;
            float pos = -logf(p + 1e-12f) * 0.25f * (om * om);
            clsval[(size_t)c * NP + i] = (pos - neg) * 2.0f;   // * CLS_W
        }
    } else if (b < PB_V0) {
#pragma clang fp contract(off)
        int j = (b - PB_G0) * 256 + threadIdx.x;
        if (j < NG) {
            float fw = (float)imgw[0], fh = (float)imgh[0];
            float4 g = ((const float4*)gb)[j];
            float gcx = (g.x + g.z) * 0.5f, gcy = (g.y + g.w) * 0.5f;
            float gw = g.z - g.x, gh = g.w - g.y;
            float4 cb; cb.x = gcx - 2.5f * gw; cb.y = gcy - 2.5f * gh;
            cb.z = gcx + 2.5f * gw; cb.w = gcy + 2.5f * gh;
            gcb[j] = cb;
            float4 Gn; Gn.x = g.x / fw; Gn.y = g.y / fh; Gn.z = g.z / fw; Gn.w = g.w / fh;
            gnm[j] = Gn;
            gar[j] = (g.z - g.x) * (g.w - g.y);
        }
    } else {
#pragma clang fp contract(off)
        int wave = threadIdx.x >> 6;
        int lane = threadIdx.x & 63;
        int i = (b - PB_V0) * 4 + wave;
        if (i >= NP) return;
        float4 p = ((const float4*)pb)[i];
        float pcx = (p.x + p.z) * 0.5f, pcy = (p.y + p.w) * 0.5f;
        int vb = 0, vc = 0;
        const float4* gb4 = (const float4*)gb;
        for (int jb = 0; jb < NG; jb += 64) {
            int j = jb + lane;
            if (j < NG) {
                float4 g = gb4[j];
                vb |= (pcx > g.x && pcx < g.z && pcy > g.y && pcy < g.w) ? 1 : 0;
                float gcx = (g.x + g.z) * 0.5f, gcy = (g.y + g.w) * 0.5f;
                float gw = g.z - g.x, gh = g.w - g.y;
                vc |= (pcx > gcx - 2.5f * gw && pcx < gcx + 2.5f * gw &&
                       pcy > gcy - 2.5f * gh && pcy < gcy + 2.5f * gh) ? 1 : 0;
            }
            if (__any(vb | vc)) break;
        }
        int any = __any(vb | vc) ? 1 : 0;
        if (lane == 0) {
            float fw = (float)imgw[0], fh = (float)imgh[0];
            float4 pn; pn.x = p.x / fw; pn.y = p.y / fh; pn.z = p.z / fw; pn.w = p.w / fh;
            pnorm[i] = pn;
            float4 pi4; pi4.x = pcx; pi4.y = pcy;
            pi4.z = (p.z - p.x) * (p.w - p.y);
            pi4.w = any ? 0.0f : 10000.0f;
            pinfo[i] = pi4;
        }
    }
}

// ---------------------------------------------------------------------------
// k_sortcopy: gather cell-sorted copies of per-pred tables (needs iorig +
// pnorm/pinfo complete -> separate launch after k_prep). Coalesced writes.
// ---------------------------------------------------------------------------
__global__ __launch_bounds__(256) void k_sortcopy(const float* __restrict__ pb,
        const float4* __restrict__ pnorm, const float4* __restrict__ pinfo,
        const int* __restrict__ iorig,
        float4* __restrict__ pbs, float4* __restrict__ pns,
        float4* __restrict__ pis)
{
    int s = blockIdx.x * 256 + threadIdx.x;
    if (s >= NP) return;
    int i = iorig[s];
    pbs[s] = ((const float4*)pb)[i];
    pns[s] = pnorm[i];
    pis[s] = pinfo[i];
}

// ---------------------------------------------------------------------------
// k_cost2: GRID-PREFILTERED direct eval (R12). Block = gt (gorder XCD
// clustering, proven R11). Candidate region = cells whose centers can belong
// to an overlapping pred (gt box expanded by measured hwmax) — avg ~870
// preds vs 10000 (11x less scanning). Candidate density ~46% -> direct
// cost_iou on hit lanes (no LDS list/compaction). Per-lane top-5 + butterfly
// wavemerge + block 4-way merge + TKEY gate (block scope, proven):
// non-scanned preds provably don't overlap -> iou = 0.0 == pads, cost >= ~59
// -> coverage argument identical to R9/R11. Redo = exact full 10000-pred
// scan on ORIGINAL arrays (R9-verbatim). Epilogue verbatim (dk, top5, row
// atomics; packkey ties broken by ORIGINAL index via iorig).
// ---------------------------------------------------------------------------
__global__ __launch_bounds__(256) void k_cost2(
        const float* __restrict__ pb, const float* __restrict__ gb,
        const int* __restrict__ glab, const float* __restrict__ clsval,
        const float4* __restrict__ pnorm, const float4* __restrict__ pinfo,
        const float4* __restrict__ gcb, const float4* __restrict__ gnm,
        const float* __restrict__ gar, const int* __restrict__ gorder,
        const float4* __restrict__ pbs, const float4* __restrict__ pns,
        const float4* __restrict__ pis, const int* __restrict__ iorig,
        const int* __restrict__ cellstart, const float* __restrict__ gridp,
        int* __restrict__ rowcnt, int* __restrict__ rowfirst,
        int* __restrict__ rowiter, int* __restrict__ top5,
        int* __restrict__ dkarr)
{
    __shared__ int s_seg[GY + 2];
    __shared__ int s_pre[GY + 2];
    __shared__ int s_nrow;
    __shared__ unsigned long long s_k4[4][5];
    __shared__ float s_iv4[4][5];
    __shared__ int s_redo;

    int bb = blockIdx.x;
    int j = gorder[(bb & 7) * (NG / 8) + (bb >> 3)];
    int tid = threadIdx.x;
    int wid = tid >> 6;
    int ln  = tid & 63;
    float4 g  = ((const float4*)gb)[j];
    float4 cb = gcb[j];
    float4 Gn = gnm[j];
    float  ga = gar[j];
    const float* clscol = clsval + (size_t)glab[j] * NP;
    const float4* pb4 = (const float4*)pb;
    int base_i = wid * CHSZ;

    // ---- cell-range segments (thread 0; all waves share the gt) ----
    if (tid == 0) {
        float R  = gridp[0];
        float cw = gridp[1];
        float ch = gridp[2];
        int cx0 = (int)floorf((g.x - R) / cw); cx0 = min(max(cx0, 0), GX - 1);
        int cx1 = (int)floorf((g.z + R) / cw); cx1 = min(max(cx1, 0), GX - 1);
        int cy0 = (int)floorf((g.y - R) / ch); cy0 = min(max(cy0, 0), GY - 1);
        int cy1 = (int)floorf((g.w + R) / ch); cy1 = min(max(cy1, 0), GY - 1);
        int nr = 0, acc = 0;
        for (int cy = cy0; cy <= cy1; cy++) {
            int s0 = cellstart[cy * GX + cx0];
            int s1 = cellstart[cy * GX + cx1 + 1];
            s_seg[nr] = s0; s_pre[nr] = acc; acc += s1 - s0; nr++;
        }
        s_pre[nr] = acc;
        s_nrow = nr;
        s_redo = 0;
    }
    __syncthreads();
    int nr = s_nrow;
    int T = s_pre[nr];
    int lo = (T * wid) >> 2;
    int hi = (T * (wid + 1)) >> 2;

    unsigned long long kv[5]; float iv[5];
#pragma unroll
    for (int t = 0; t < 5; t++) { kv[t] = KMAX; iv[t] = 0.0f; }

    // ---- direct scan+eval over the wave's slice of the candidate span ----
    for (int v = lo + ln; v < hi; v += 64) {
        int rr = 0;
        while (s_pre[rr + 1] <= v) rr++;          // <= nr-1 iterations
        int s = s_seg[rr] + (v - s_pre[rr]);
        float4 p = pbs[s];
        bool o = (p.z > g.x) & (g.z > p.x) & (p.w > g.y) & (g.w > p.y);
        if (o) {
            int io = iorig[s];
            float cc, iou;
            cost_iou(p, pns[s], pis[s], g, cb, Gn, ga, clscol[io], cc, iou);
            ins5k(kv, packkey(cc, io)); ins5i(iv, iou);
        }
    }
    wavemerge5(kv, iv);

    if (ln == 0) {
#pragma unroll
        for (int t = 0; t < 5; t++) { s_k4[wid][t] = kv[t]; s_iv4[wid][t] = iv[t]; }
    }
    __syncthreads();

    unsigned long long mk0=KMAX, mk1=KMAX, mk2=KMAX, mk3=KMAX, mk4=KMAX;
    float mi0=-2.0f, mi1=-2.0f, mi2=-2.0f, mi3=-2.0f, mi4=-2.0f;
    if (tid == 0) {
        int h0 = 0, h1 = 0, h2 = 0, h3 = 0;
        unsigned long long mk[5];
#pragma unroll
        for (int r = 0; r < 5; r++) {
            unsigned long long v0 = (h0 < 5) ? s_k4[0][h0] : KMAX;
            unsigned long long v1 = (h1 < 5) ? s_k4[1][h1] : KMAX;
            unsigned long long v2 = (h2 < 5) ? s_k4[2][h2] : KMAX;
            unsigned long long v3 = (h3 < 5) ? s_k4[3][h3] : KMAX;
            unsigned long long best = v0; int sel = 0;
            if (v1 < best) { best = v1; sel = 1; }
            if (v2 < best) { best = v2; sel = 2; }
            if (v3 < best) { best = v3; sel = 3; }
            mk[r] = best;
            h0 += (sel == 0); h1 += (sel == 1); h2 += (sel == 2); h3 += (sel == 3);
        }
        int g0 = 0, g1 = 0, g2 = 0, g3 = 0;
        float mi[5];
#pragma unroll
        for (int r = 0; r < 5; r++) {
            float w0 = (g0 < 5) ? s_iv4[0][g0] : -2.0f;
            float w1 = (g1 < 5) ? s_iv4[1][g1] : -2.0f;
            float w2 = (g2 < 5) ? s_iv4[2][g2] : -2.0f;
            float w3 = (g3 < 5) ? s_iv4[3][g3] : -2.0f;
            float best = w0; int sel = 0;
            if (w1 > best) { best = w1; sel = 1; }
            if (w2 > best) { best = w2; sel = 2; }
            if (w3 > best) { best = w3; sel = 3; }
            mi[r] = best;
            g0 += (sel == 0); g1 += (sel == 1); g2 += (sel == 2); g3 += (sel == 3);
        }
        mk0 = mk[0]; mk1 = mk[1]; mk2 = mk[2]; mk3 = mk[3]; mk4 = mk[4];
        mi0 = mi[0]; mi1 = mi[1]; mi2 = mi[2]; mi3 = mi[3]; mi4 = mi[4];
        s_redo = (mk4 >= TKEY) ? 1 : 0;
    }
    __syncthreads();

    if (s_redo) {
        // exact full rescan over ALL 10000 preds (R9-verbatim, orig arrays)
#pragma unroll
        for (int t = 0; t < 5; t++) { kv[t] = KMAX; iv[t] = -1.0f; }
        for (int k = 0; k <= WMAIN; k++) {
            bool valid = (k < WMAIN) | (ln < WTAIL);
            if (valid) {
                int i = base_i + ln + k * 64;
                float cc, iou;
                cost_iou(pb4[i], pnorm[i], pinfo[i], g, cb, Gn, ga, clscol[i], cc, iou);
                ins5k(kv, packkey(cc, i)); ins5i(iv, iou);
            }
        }
        wavemerge5(kv, iv);
        if (ln == 0) {
#pragma unroll
            for (int t = 0; t < 5; t++) { s_k4[wid][t] = kv[t]; s_iv4[wid][t] = iv[t]; }
        }
        __syncthreads();
        if (tid == 0) {
            int h0 = 0, h1 = 0, h2 = 0, h3 = 0;
            unsigned long long mk[5];
#pragma unroll
            for (int r = 0; r < 5; r++) {
                unsigned long long v0 = (h0 < 5) ? s_k4[0][h0] : KMAX;
                unsigned long long v1 = (h1 < 5) ? s_k4[1][h1] : KMAX;
                unsigned long long v2 = (h2 < 5) ? s_k4[2][h2] : KMAX;
                unsigned long long v3 = (h3 < 5) ? s_k4[3][h3] : KMAX;
                unsigned long long best = v0; int sel = 0;
                if (v1 < best) { best = v1; sel = 1; }
                if (v2 < best) { best = v2; sel = 2; }
                if (v3 < best) { best = v3; sel = 3; }
                mk[r] = best;
                h0 += (sel == 0); h1 += (sel == 1); h2 += (sel == 2); h3 += (sel == 3);
            }
            int g0 = 0, g1 = 0, g2 = 0, g3 = 0;
            float mi[5];
#pragma unroll
            for (int r = 0; r < 5; r++) {
                float w0 = (g0 < 5) ? s_iv4[0][g0] : -2.0f;
                float w1 = (g1 < 5) ? s_iv4[1][g1] : -2.0f;
                float w2 = (g2 < 5) ? s_iv4[2][g2] : -2.0f;
                float w3 = (g3 < 5) ? s_iv4[3][g3] : -2.0f;
                float best = w0; int sel = 0;
                if (w1 > best) { best = w1; sel = 1; }
                if (w2 > best) { best = w2; sel = 2; }
                if (w3 > best) { best = w3; sel = 3; }
                mi[r] = best;
                g0 += (sel == 0); g1 += (sel == 1); g2 += (sel == 2); g3 += (sel == 3);
            }
            mk0 = mk[0]; mk1 = mk[1]; mk2 = mk[2]; mk3 = mk[3]; mk4 = mk[4];
            mi0 = mi[0]; mi1 = mi[1]; mi2 = mi[2]; mi3 = mi[3]; mi4 = mi[4];
        }
    }

    if (tid == 0) {
        float s = (((mi0 + mi1) + mi2) + mi3) + mi4;
        int dk = (int)s;                 // astype(int32): truncation
        if (dk < 1) dk = 1;
        dkarr[j] = dk;
        int b0 = keyidx(mk0), b1 = keyidx(mk1), b2 = keyidx(mk2);
        int b3 = keyidx(mk3), b4 = keyidx(mk4);
        top5[j * 5 + 0] = b0; top5[j * 5 + 1] = b1; top5[j * 5 + 2] = b2;
        top5[j * 5 + 3] = b3; top5[j * 5 + 4] = b4;
#pragma unroll
        for (int t = 0; t < 5; t++) {
            int r = (t == 0) ? b0 : (t == 1) ? b1 : (t == 2) ? b2
                  : (t == 3) ? b3 : b4;
            if (t < dk) {
                atomicAdd(&rowcnt[r], 1);
                atomicMin(&rowfirst[r], j);
                atomicMin(&rowiter[r], -1);   // initially matched
            }
        }
    }
}

// ---------------------------------------------------------------------------
// Fused prior-detect + pfix + surv (R10/R11, verbatim: rowcost caching).
// ---------------------------------------------------------------------------
__global__ __launch_bounds__(256) void k_pfixsurv(const float* __restrict__ pb,
        const float* __restrict__ gb, const int* __restrict__ glab,
        const float* __restrict__ clsval,
        const float4* __restrict__ pnorm, const float4* __restrict__ pinfo,
        const float4* __restrict__ gcb, const float4* __restrict__ gnm,
        const float* __restrict__ gar,
        int* __restrict__ prior, int* __restrict__ priorcol,
        int* __restrict__ colsum,
        const int* __restrict__ rowcnt, const int* __restrict__ top5,
        const int* __restrict__ dkarr,
        int* __restrict__ scal, int* __restrict__ priorslot,
        float* __restrict__ rowcost)
{
    int b = blockIdx.x;
    int tid = threadIdx.x;
    if (b >= 2500) {
        int j = (b - 2500) * 256 + tid;
        if (j >= NG) return;
        int c = 0;
        int dk = dkarr[j];
        for (int t = 0; t < dk; t++) if (rowcnt[top5[j * 5 + t]] == 1) c++;
        if (c) atomicAdd(&colsum[j], c);
        return;
    }
    __shared__ float rv[256]; __shared__ int ri[256];
    __shared__ int s_slot;
    for (int q = 0; q < 4; q++) {
        int row = b * 4 + q;
        if (rowcnt[row] <= 1) continue;      // uniform across block
        if (tid == 0) {
            prior[row] = 1;
            int s = atomicAdd(&scal[20], 1);
            int sl = (s < PSLOTS) ? s : -1;
            priorslot[row] = sl;
            s_slot = sl;
        }
        __syncthreads();
        int slot = s_slot;
        float* rc = (slot >= 0) ? (rowcost + (size_t)slot * NG) : nullptr;
        float4 p = ((const float4*)pb)[row];
        float4 pn = pnorm[row];
        float4 pi4 = pinfo[row];
        float best = FLT_MAX; int bj = 0x7fffffff;
        for (int j = tid; j < NG; j += 256) {
            float cc, iou;
            cost_iou(p, pn, pi4, ((const float4*)gb)[j], gcb[j], gnm[j], gar[j],
                     clsval[(size_t)glab[j] * NP + row], cc, iou);
            if (rc) rc[j] = cc;
            if (lexless(cc, j, best, bj)) { best = cc; bj = j; }
        }
        rv[tid] = best; ri[tid] = bj; __syncthreads();
        for (int w = 128; w > 0; w >>= 1) {
            if (tid < w) {
                float ov = rv[tid + w]; int oi = ri[tid + w];
                if (lexless(ov, oi, rv[tid], ri[tid])) { rv[tid] = ov; ri[tid] = oi; }
            }
            __syncthreads();
        }
        if (tid == 0) {
            priorcol[row] = ri[0];
            atomicAdd(&colsum[ri[0]], 1);
        }
        __syncthreads();
    }
}

// ---------------------------------------------------------------------------
// k_dyn (R10/R11, verbatim, proven): single-workgroup fusion of the 12
// iterB/C launches + final; true __syncthreads barriers; early break.
// ---------------------------------------------------------------------------
__global__ __launch_bounds__(1024) void k_dyn(
        const float* __restrict__ pb, const float* __restrict__ gb,
        const int* __restrict__ glab, const float* __restrict__ clsval,
        const float4* __restrict__ pnorm, const float4* __restrict__ pinfo,
        const float4* __restrict__ gcb, const float4* __restrict__ gnm,
        const float* __restrict__ gar,
        const int* __restrict__ top5, int* __restrict__ rowiter,
        int* __restrict__ rowcnt, int* __restrict__ rowfirst,
        int* __restrict__ colsum, const int* __restrict__ prior,
        int* __restrict__ priorcol, const int* __restrict__ priorslot,
        const float* __restrict__ rowcost, int* __restrict__ out)
{
    __shared__ int s_plist[PCAP];
    __shared__ int s_flist[FCAP];
    __shared__ int s_pcnt;
    __shared__ int s_fcnt;
    __shared__ int s_body;
    __shared__ int s_multi;

    int tid = threadIdx.x;
    int wid = tid >> 6;
    int ln  = tid & 63;
    const float4* pb4 = (const float4*)pb;

    if (tid == 0) { s_pcnt = 0; s_multi = 0; }
    __syncthreads();
    for (int i = tid; i < NP; i += 1024) {
        if (prior[i]) {
            int s = atomicAdd(&s_pcnt, 1);
            if (s < PCAP) s_plist[s] = i;
        }
    }
    __syncthreads();
    int pcnt = (s_pcnt < PCAP) ? s_pcnt : PCAP;

    for (int t = 0; t < LMAX; t++) {
        if (tid == 0) { s_body = 0; s_fcnt = 0; }
        __threadfence();
        __syncthreads();

        // ---- B fast path: thread per column ----
        for (int j = tid; j < NG; j += 1024) {
            if (colsum[j] != 0) continue;
            s_body = 1;                       // benign race (all write 1)
            int pos = -1;
            for (int r = 0; r < 5; r++) {
                int i = top5[j * 5 + r];
                if (rowiter[i] >= t) { pos = i; break; }
            }
            if (pos < 0) {
                int f = atomicAdd(&s_fcnt, 1);
                if (f < FCAP) s_flist[f] = j;   // FCAP >= NG: no overflow
                continue;
            }
            colsum[j] = 1;
            int old = atomicAdd(&rowcnt[pos], 1);
            if (old >= 1) s_multi = 1;
            atomicMin(&rowfirst[pos], j);
            atomicMin(&rowiter[pos], t);
        }
        __threadfence();
        __syncthreads();

        // ---- B fallback: wave per queued column ----
        int fcnt = (s_fcnt < FCAP) ? s_fcnt : FCAP;
        for (int q = wid; q < fcnt; q += 16) {
            int j = s_flist[q];
            float4 g  = ((const float4*)gb)[j];
            float4 cb = gcb[j];
            float4 Gn = gnm[j];
            float  ga = gar[j];
            const float* clscol = clsval + (size_t)glab[j] * NP;
            float best = FLT_MAX; int bi = 0x7fffffff;
            for (int i = ln; i < NP; i += 64) {
                if (rowiter[i] < t) continue;
                float cc, iou;
                cost_iou(pb4[i], pnorm[i], pinfo[i], g, cb, Gn, ga, clscol[i], cc, iou);
                if (lexless(cc, i, best, bi)) { best = cc; bi = i; }
            }
            wavered_lex(best, bi);
            if (ln == 0) {
                colsum[j] = 1;
                int old = atomicAdd(&rowcnt[bi], 1);
                if (old >= 1) s_multi = 1;
                atomicMin(&rowfirst[bi], j);
                atomicMin(&rowiter[bi], t);
            }
        }
        __threadfence();
        __syncthreads();

        if (!s_body) break;                  // reference while-cond fixpoint

        // ---- C (m_fix): wave per prior row, iff sticky multi ----
        if (s_multi) {
            for (int q = wid; q < pcnt; q += 16) {
                int row = s_plist[q];
                int k = t - rowiter[row]; if (k < 0) k = 0;  // prior: -1 -> t+1
                int slot = priorslot[row];
                float best = FLT_MAX; int bj = 0x7fffffff;
                if (slot >= 0) {
                    const float* rc = rowcost + (size_t)slot * NG;
                    for (int j = ln; j < NG; j += 64) {
                        float val = inflate(rc[j], k);
                        if (lexless(val, j, best, bj)) { best = val; bj = j; }
                    }
                } else {
                    float4 p = pb4[row];
                    float4 pn = pnorm[row];
                    float4 pi4 = pinfo[row];
                    for (int j = ln; j < NG; j += 64) {
                        float cc, iou;
                        cost_iou(p, pn, pi4, ((const float4*)gb)[j], gcb[j],
                                 gnm[j], gar[j],
                                 clsval[(size_t)glab[j] * NP + row], cc, iou);
                        float val = inflate(cc, k);
                        if (lexless(val, j, best, bj)) { best = val; bj = j; }
                    }
                }
                wavered_lex(best, bj);
                if (ln == 0) {
                    int nb = bj;
                    int oldc = priorcol[row];
                    if (nb != oldc) {
                        atomicSub(&colsum[oldc], 1);
                        atomicAdd(&colsum[nb], 1);
                        priorcol[row] = nb;
                    }
                }
            }
        }
        __threadfence();
        __syncthreads();
    }

    // ---- final (folded) ----
    __threadfence();
    __syncthreads();
    for (int i = tid; i < NP; i += 1024) {
        int fg = rowcnt[i] > 0;
        out[i] = fg ? 1 : 0;
        out[NP + i] = fg ? (prior[i] ? priorcol[i] : rowfirst[i]) : 0;
    }
}

extern "C" void kernel_launch(void* const* d_in, const int* in_sizes, int n_in,
                              void* d_out, int out_size, void* d_ws, size_t ws_size,
                              hipStream_t stream)
{
    (void)in_sizes; (void)n_in; (void)out_size; (void)ws_size;
    const float* logits = (const float*)d_in[0];
    const float* pboxes = (const float*)d_in[1];
    const float* gboxes = (const float*)d_in[2];
    const int*   glab   = (const int*)d_in[3];
    const int*   imgh   = (const int*)d_in[4];
    const int*   imgw   = (const int*)d_in[5];
    int* out = (int*)d_out;

    char* w = (char*)d_ws;
    float*  clsval  = (float*)(w);                    // 3,200,000
    float4* pnorm   = (float4*)(w + 3200000);         //   160,000
    float4* pinfo   = (float4*)(w + 3360000);         //   160,000
    float4* gcb     = (float4*)(w + 3520000);         //    16,000
    float4* gnm     = (float4*)(w + 3536000);         //    16,000
    float*  gar     = (float*)(w + 3552000);          //     4,000
    int* rowcnt     = (int*)(w + 3556000);            //    40,000
    int* rowfirst   = (int*)(w + 3596000);            //    40,000
    int* rowiter    = (int*)(w + 3636000);            //    40,000
    int* prior      = (int*)(w + 3676000);            //    40,000
    int* priorcol   = (int*)(w + 3716000);            //    40,000
    int* top5       = (int*)(w + 3756000);            //    20,000
    int* dkarr      = (int*)(w + 3776000);            //     4,000
    int* colsum     = (int*)(w + 3780000);            //     4,000
    int* scal       = (int*)(w + 3784000);            //       128
    int* priorslot  = (int*)(w + 3784128);            //    40,000
    int* gorder     = (int*)(w + 3824128);            //     4,000
    float* rowcost  = (float*)(w + 3828128);          // 10,240,000 (2560x1000)
    float4* pbs     = (float4*)(w + 14068128);        //   160,000
    float4* pns     = (float4*)(w + 14228128);        //   160,000
    float4* pis     = (float4*)(w + 14388128);        //   160,000
    int* iorig      = (int*)(w + 14548128);           //    40,000
    int* cellstart  = (int*)(w + 14588128);           //     1,024 (161 used)
    float* gridp    = (float*)(w + 14589152);         //       128

    hipLaunchKernelGGL(k_prep, dim3(2703), dim3(256), 0, stream,
                       logits, pboxes, gboxes, glab, imgw, imgh,
                       clsval, pnorm, pinfo, gcb, gnm, gar,
                       rowcnt, rowfirst, rowiter, prior, priorcol, colsum, scal,
                       priorslot, gorder, iorig, cellstart, gridp);
    hipLaunchKernelGGL(k_sortcopy, dim3(40), dim3(256), 0, stream,
                       pboxes, pnorm, pinfo, iorig, pbs, pns, pis);
    hipLaunchKernelGGL(k_cost2, dim3(NG), dim3(256), 0, stream,
                       pboxes, gboxes, glab, clsval, pnorm, pinfo, gcb, gnm, gar,
                       gorder, pbs, pns, pis, iorig, cellstart, gridp,
                       rowcnt, rowfirst, rowiter, top5, dkarr);
    hipLaunchKernelGGL(k_pfixsurv, dim3(2504), dim3(256), 0, stream,
                       pboxes, gboxes, glab, clsval, pnorm, pinfo, gcb, gnm, gar,
                       prior, priorcol, colsum, rowcnt, top5, dkarr,
                       scal, priorslot, rowcost);
    hipLaunchKernelGGL(k_dyn, dim3(1), dim3(1024), 0, stream,
                       pboxes, gboxes, glab, clsval, pnorm, pinfo, gcb, gnm, gar,
                       top5, rowiter, rowcnt, rowfirst, colsum, prior,
                       priorcol, priorslot, rowcost, out);
}

// Round 13
// 169.212 us; speedup vs baseline: 1.1283x; 1.1283x over previous
//
#include <hip/hip_runtime.h>
#include <cfloat>
#include <cmath>

#define NP 10000
#define NG 1000
#define NC 80
#define LMAX 6
#define NCH 4
#define CHSZ (NP / NCH)     // 2500 preds per wave-task (redo path)
#define WMAIN 39            // 39*64 = 2496
#define WTAIL 4             // + 4 = 2500

#define RI_BIG  0x3fffffff
#define KMAX    0xFFFFFFFFFFFFFFFFull

// packkey(50.0f,0): strong (inb) costs < ~28, non-strong >= ~59. Block-scope
// gate (proven R9/R11/R12): merged 5th key >= TKEY -> exact full rescan.
#define TKEY    0xC248000000000000ull

// spatial grid: 16 x 10 cells over the image; preds binned by center.
#define GX 16
#define GY 10
#define NCELL (GX * GY)

// prior-row cost cache: slots x 1000 floats (prior rows <= 2500)
#define PSLOTS  2560
#define PCAP    2560
#define FCAP    1024

__device__ __forceinline__ bool lexless(float av, int ai, float bv, int bi) {
    return (av < bv) || (av == bv && ai < bi);
}

// float -> order-preserving u32 (no NaNs in this data), packed with index.
__device__ __forceinline__ unsigned long long packkey(float v, int idx) {
    unsigned u = __float_as_uint(v);
    u ^= (unsigned)(((int)u) >> 31) | 0x80000000u;
    return ((unsigned long long)u << 32) | (unsigned)idx;
}
__device__ __forceinline__ int keyidx(unsigned long long k) {
    return (int)(unsigned)(k & 0xFFFFFFFFu);
}

// Exact sequential +1e5 inflation (reference adds 1e5 once per loop iter).
__device__ __forceinline__ float inflate(float c, int k) {
    for (int q = 0; q < k; q++) c += 100000.0f;
    return c;
}

// Per-pair cost+iou from precomputed tables. Contraction OFF so every kernel
// that recomputes cost(i,j) agrees bit-exactly.
__device__ __forceinline__ void cost_iou(float4 p, float4 pn, float4 pi,
        float4 g, float4 cb, float4 Gn, float ga, float clsv,
        float& cc_out, float& iou_out) {
#pragma clang fp contract(off)
    float wx = fminf(p.z, g.z) - fmaxf(p.x, g.x); wx = fmaxf(wx, 0.0f);
    float wy = fminf(p.w, g.w) - fmaxf(p.y, g.y); wy = fmaxf(wy, 0.0f);
    float inter = wx * wy;
    float uni = pi.z + ga - inter;
    float iou = inter / fmaxf(uni, 1e-12f);
    float ex = fmaxf(p.z, g.z) - fminf(p.x, g.x); ex = fmaxf(ex, 0.0f);
    float ey = fmaxf(p.w, g.w) - fminf(p.y, g.y); ey = fmaxf(ey, 0.0f);
    float enc = ex * ey;
    float giou = iou - (enc - uni) / fmaxf(enc, 1e-12f);
    float l1 = ((fabsf(pn.x - Gn.x) + fabsf(pn.y - Gn.y))
                + fabsf(pn.z - Gn.z)) + fabsf(pn.w - Gn.w);
    float cc = clsv + l1 * 5.0f;
    cc = cc + (-giou * 2.0f);
    bool inb = (pi.x > g.x && pi.x < g.z && pi.y > g.y && pi.y < g.w);
    bool inc = (pi.x > cb.x && pi.x < cb.z && pi.y > cb.y && pi.y < cb.w);
    cc = cc + ((inb && inc) ? 0.0f : 100.0f);
    cc = cc + pi.w;
    cc_out = cc; iou_out = iou;
}

// Proven per-lane sorted top-5 insertion (static indices after unroll).
__device__ __forceinline__ void ins5k(unsigned long long* kv,
        unsigned long long key) {
    if (key < kv[4]) {
        kv[4] = key;
#pragma unroll
        for (int t = 4; t > 0; t--)
            if (kv[t] < kv[t-1]) { unsigned long long tv = kv[t]; kv[t] = kv[t-1]; kv[t-1] = tv; }
    }
}
__device__ __forceinline__ void ins5i(float* iv, float iou) {
    if (iou > iv[4]) {
        iv[4] = iou;
#pragma unroll
        for (int t = 4; t > 0; t--)
            if (iv[t] > iv[t-1]) { float tv = iv[t]; iv[t] = iv[t-1]; iv[t-1] = tv; }
    }
}

// static 9-comparator sorting networks for 5 elements (constant indices only)
__device__ __forceinline__ void cswapk(unsigned long long& a,
        unsigned long long& b) {
    unsigned long long lo = (a < b) ? a : b;
    unsigned long long hi = (a < b) ? b : a;
    a = lo; b = hi;
}
__device__ __forceinline__ void sort5k(unsigned long long* a) {   // ascending
    cswapk(a[0],a[1]); cswapk(a[3],a[4]); cswapk(a[2],a[4]);
    cswapk(a[2],a[3]); cswapk(a[1],a[4]); cswapk(a[0],a[3]);
    cswapk(a[0],a[2]); cswapk(a[1],a[3]); cswapk(a[1],a[2]);
}
__device__ __forceinline__ void cswapi(float& a, float& b) {      // a=max
    float hi = fmaxf(a, b), lo = fminf(a, b);
    a = hi; b = lo;
}
__device__ __forceinline__ void sort5i(float* a) {                // descending
    cswapi(a[0],a[1]); cswapi(a[3],a[4]); cswapi(a[2],a[4]);
    cswapi(a[2],a[3]); cswapi(a[1],a[4]); cswapi(a[0],a[3]);
    cswapi(a[0],a[2]); cswapi(a[1],a[3]); cswapi(a[1],a[2]);
}

// 6-round butterfly allreduce of sorted 5-lists across the 64-lane wave
// (proven R8-R12 on hardware).
__device__ __forceinline__ void wavemerge5(unsigned long long* kv, float* iv) {
#pragma unroll
    for (int d = 1; d < 64; d <<= 1) {
        unsigned long long r0 = __shfl_xor(kv[0], d);
        unsigned long long r1 = __shfl_xor(kv[1], d);
        unsigned long long r2 = __shfl_xor(kv[2], d);
        unsigned long long r3 = __shfl_xor(kv[3], d);
        unsigned long long r4 = __shfl_xor(kv[4], d);
        kv[0] = (kv[0] < r4) ? kv[0] : r4;
        kv[1] = (kv[1] < r3) ? kv[1] : r3;
        kv[2] = (kv[2] < r2) ? kv[2] : r2;
        kv[3] = (kv[3] < r1) ? kv[3] : r1;
        kv[4] = (kv[4] < r0) ? kv[4] : r0;
        sort5k(kv);
        float s0 = __shfl_xor(iv[0], d);
        float s1 = __shfl_xor(iv[1], d);
        float s2 = __shfl_xor(iv[2], d);
        float s3 = __shfl_xor(iv[3], d);
        float s4 = __shfl_xor(iv[4], d);
        iv[0] = fmaxf(iv[0], s4);
        iv[1] = fmaxf(iv[1], s3);
        iv[2] = fmaxf(iv[2], s2);
        iv[3] = fmaxf(iv[3], s1);
        iv[4] = fmaxf(iv[4], s0);
        sort5i(iv);
    }
}

// butterfly allreduce of lexless-argmin (val asc, idx asc) across a wave
__device__ __forceinline__ void wavered_lex(float& best, int& bi) {
#pragma unroll
    for (int d = 1; d < 64; d <<= 1) {
        float ov = __shfl_xor(best, d);
        int oi = __shfl_xor(bi, d);
        if (lexless(ov, oi, best, bi)) { best = ov; bi = oi; }
    }
}

// ---------------------------------------------------------------------------
// Fused prep (R12 verbatim). Block ranges:
//  [0,40): init state; [40,197): cls table; [197,201): per-gt tables;
//  [201,2701): wave-per-pred validity + per-pred tables;
//  2701: label counting-sort -> gorder; 2702: spatial grid build.
// ---------------------------------------------------------------------------
#define CLS_TI 64
#define PB_CLS0 40
#define PB_G0   197
#define PB_V0   201
#define PB_SORT 2701
#define PB_GRID 2702
__global__ __launch_bounds__(256) void k_prep(const float* __restrict__ logits,
        const float* __restrict__ pb, const float* __restrict__ gb,
        const int* __restrict__ glab,
        const int* __restrict__ imgw, const int* __restrict__ imgh,
        float* __restrict__ clsval, float4* __restrict__ pnorm,
        float4* __restrict__ pinfo, float4* __restrict__ gcb,
        float4* __restrict__ gnm, float* __restrict__ gar,
        int* rowcnt, int* rowfirst, int* rowiter, int* prior, int* priorcol,
        int* colsum, int* scal, int* priorslot, int* gorder,
        int* __restrict__ iorig, int* __restrict__ cellstart,
        float* __restrict__ gridp)
{
    __shared__ float sl[CLS_TI * (NC + 1)];
    int b = blockIdx.x;
    if (b == PB_GRID) {
        __shared__ int hist[NCELL];
        __shared__ int basec[NCELL];
        __shared__ float shw[256];
        int tid = threadIdx.x;
        float cw = (float)imgw[0] / (float)GX;
        float ch = (float)imgh[0] / (float)GY;
        for (int c = tid; c < NCELL; c += 256) hist[c] = 0;
        __syncthreads();
        float hwm = 0.0f;
        const float4* pb4 = (const float4*)pb;
        for (int i = tid; i < NP; i += 256) {
            float4 p = pb4[i];
            float pcx = (p.x + p.z) * 0.5f, pcy = (p.y + p.w) * 0.5f;
            hwm = fmaxf(hwm, fmaxf((p.z - p.x) * 0.5f, (p.w - p.y) * 0.5f));
            int cx = (int)(pcx / cw); cx = min(max(cx, 0), GX - 1);
            int cy = (int)(pcy / ch); cy = min(max(cy, 0), GY - 1);
            atomicAdd(&hist[cy * GX + cx], 1);
        }
        shw[tid] = hwm;
        __syncthreads();
        for (int w = 128; w > 0; w >>= 1) {
            if (tid < w) shw[tid] = fmaxf(shw[tid], shw[tid + w]);
            __syncthreads();
        }
        if (tid == 0) {
            gridp[0] = shw[0];
            gridp[1] = cw;
            gridp[2] = ch;
            int acc = 0;
            for (int c = 0; c < NCELL; c++) {
                cellstart[c] = acc; basec[c] = acc; acc += hist[c];
            }
            cellstart[NCELL] = acc;     // == NP
        }
        __syncthreads();
        for (int i = tid; i < NP; i += 256) {
            float4 p = pb4[i];
            float pcx = (p.x + p.z) * 0.5f, pcy = (p.y + p.w) * 0.5f;
            int cx = (int)(pcx / cw); cx = min(max(cx, 0), GX - 1);
            int cy = (int)(pcy / ch); cy = min(max(cy, 0), GY - 1);
            int pos = atomicAdd(&basec[cy * GX + cx], 1);
            iorig[pos] = i;
        }
        return;
    }
    if (b == PB_SORT) {
        __shared__ int hist[NC];
        __shared__ int basec[NC];
        int tid = threadIdx.x;
        if (tid < NC) hist[tid] = 0;
        __syncthreads();
        for (int j = tid; j < NG; j += 256) atomicAdd(&hist[glab[j]], 1);
        __syncthreads();
        if (tid == 0) {
            int acc = 0;
            for (int c = 0; c < NC; c++) { basec[c] = acc; acc += hist[c]; }
        }
        __syncthreads();
        for (int j = tid; j < NG; j += 256) {
            int pos = atomicAdd(&basec[glab[j]], 1);
            gorder[pos] = j;
        }
        return;
    }
    if (b < PB_CLS0) {
        int i = b * 256 + threadIdx.x;
        if (i < NP) {
            rowcnt[i] = 0; rowfirst[i] = 0x7fffffff; rowiter[i] = RI_BIG;
            prior[i] = 0; priorcol[i] = 0; priorslot[i] = -1;
        }
        if (i < NG) colsum[i] = 0;
        if (i < 32) scal[i] = 0;
    } else if (b < PB_G0) {
        int i0 = (b - PB_CLS0) * CLS_TI;
        bool full = (i0 + CLS_TI) <= NP;
        if (full) {
            const float* src = logits + (size_t)i0 * NC;
            for (int e = threadIdx.x; e < CLS_TI * NC; e += 256) {
                int di = e / NC, c = e - di * NC;
                sl[di * (NC + 1) + c] = src[e];
            }
        } else {
            for (int e = threadIdx.x; e < CLS_TI * NC; e += 256) {
                int di = e / NC, c = e - di * NC;
                int i = i0 + di;
                sl[di * (NC + 1) + c] = (i < NP) ? logits[(size_t)i * NC + c] : 0.0f;
            }
        }
        __syncthreads();
        for (int e = threadIdx.x; e < CLS_TI * NC; e += 256) {
            int c = e >> 6, di = e & 63;
            int i = i0 + di;
            if (i >= NP) continue;
            float x = sl[di * (NC + 1) + c];
            float p = 1.0f / (1.0f + expf(-x));
            float neg = -log1pf(-(p - 1e-12f)) * 0.75f * (p * p);
            float om = 1.0f - p;
            float pos = -logf(p + 1e-12f) * 0.25f * (om * om);
            clsval[(size_t)c * NP + i] = (pos - neg) * 2.0f;   // * CLS_W
        }
    } else if (b < PB_V0) {
#pragma clang fp contract(off)
        int j = (b - PB_G0) * 256 + threadIdx.x;
        if (j < NG) {
            float fw = (float)imgw[0], fh = (float)imgh[0];
            float4 g = ((const float4*)gb)[j];
            float gcx = (g.x + g.z) * 0.5f, gcy = (g.y + g.w) * 0.5f;
            float gw = g.z - g.x, gh = g.w - g.y;
            float4 cb; cb.x = gcx - 2.5f * gw; cb.y = gcy - 2.5f * gh;
            cb.z = gcx + 2.5f * gw; cb.w = gcy + 2.5f * gh;
            gcb[j] = cb;
            float4 Gn; Gn.x = g.x / fw; Gn.y = g.y / fh; Gn.z = g.z / fw; Gn.w = g.w / fh;
            gnm[j] = Gn;
            gar[j] = (g.z - g.x) * (g.w - g.y);
        }
    } else {
#pragma clang fp contract(off)
        int wave = threadIdx.x >> 6;
        int lane = threadIdx.x & 63;
        int i = (b - PB_V0) * 4 + wave;
        if (i >= NP) return;
        float4 p = ((const float4*)pb)[i];
        float pcx = (p.x + p.z) * 0.5f, pcy = (p.y + p.w) * 0.5f;
        int vb = 0, vc = 0;
        const float4* gb4 = (const float4*)gb;
        for (int jb = 0; jb < NG; jb += 64) {
            int j = jb + lane;
            if (j < NG) {
                float4 g = gb4[j];
                vb |= (pcx > g.x && pcx < g.z && pcy > g.y && pcy < g.w) ? 1 : 0;
                float gcx = (g.x + g.z) * 0.5f, gcy = (g.y + g.w) * 0.5f;
                float gw = g.z - g.x, gh = g.w - g.y;
                vc |= (pcx > gcx - 2.5f * gw && pcx < gcx + 2.5f * gw &&
                       pcy > gcy - 2.5f * gh && pcy < gcy + 2.5f * gh) ? 1 : 0;
            }
            if (__any(vb | vc)) break;
        }
        int any = __any(vb | vc) ? 1 : 0;
        if (lane == 0) {
            float fw = (float)imgw[0], fh = (float)imgh[0];
            float4 pn; pn.x = p.x / fw; pn.y = p.y / fh; pn.z = p.z / fw; pn.w = p.w / fh;
            pnorm[i] = pn;
            float4 pi4; pi4.x = pcx; pi4.y = pcy;
            pi4.z = (p.z - p.x) * (p.w - p.y);
            pi4.w = any ? 0.0f : 10000.0f;
            pinfo[i] = pi4;
        }
    }
}

// ---------------------------------------------------------------------------
// k_sortcopy (R12 verbatim): gather cell-sorted copies of per-pred tables.
// ---------------------------------------------------------------------------
__global__ __launch_bounds__(256) void k_sortcopy(const float* __restrict__ pb,
        const float4* __restrict__ pnorm, const float4* __restrict__ pinfo,
        const int* __restrict__ iorig,
        float4* __restrict__ pbs, float4* __restrict__ pns,
        float4* __restrict__ pis)
{
    int s = blockIdx.x * 256 + threadIdx.x;
    if (s >= NP) return;
    int i = iorig[s];
    pbs[s] = ((const float4*)pb)[i];
    pns[s] = pnorm[i];
    pis[s] = pinfo[i];
}

// ---------------------------------------------------------------------------
// k_cost2 (R12 verbatim, proven: grid-prefiltered direct eval + TKEY gate +
// full-rescan redo + folded costmerge epilogue; gorder XCD clustering).
// ---------------------------------------------------------------------------
__global__ __launch_bounds__(256) void k_cost2(
        const float* __restrict__ pb, const float* __restrict__ gb,
        const int* __restrict__ glab, const float* __restrict__ clsval,
        const float4* __restrict__ pnorm, const float4* __restrict__ pinfo,
        const float4* __restrict__ gcb, const float4* __restrict__ gnm,
        const float* __restrict__ gar, const int* __restrict__ gorder,
        const float4* __restrict__ pbs, const float4* __restrict__ pns,
        const float4* __restrict__ pis, const int* __restrict__ iorig,
        const int* __restrict__ cellstart, const float* __restrict__ gridp,
        int* __restrict__ rowcnt, int* __restrict__ rowfirst,
        int* __restrict__ rowiter, int* __restrict__ top5,
        int* __restrict__ dkarr)
{
    __shared__ int s_seg[GY + 2];
    __shared__ int s_pre[GY + 2];
    __shared__ int s_nrow;
    __shared__ unsigned long long s_k4[4][5];
    __shared__ float s_iv4[4][5];
    __shared__ int s_redo;

    int bb = blockIdx.x;
    int j = gorder[(bb & 7) * (NG / 8) + (bb >> 3)];
    int tid = threadIdx.x;
    int wid = tid >> 6;
    int ln  = tid & 63;
    float4 g  = ((const float4*)gb)[j];
    float4 cb = gcb[j];
    float4 Gn = gnm[j];
    float  ga = gar[j];
    const float* clscol = clsval + (size_t)glab[j] * NP;
    const float4* pb4 = (const float4*)pb;
    int base_i = wid * CHSZ;

    if (tid == 0) {
        float R  = gridp[0];
        float cw = gridp[1];
        float ch = gridp[2];
        int cx0 = (int)floorf((g.x - R) / cw); cx0 = min(max(cx0, 0), GX - 1);
        int cx1 = (int)floorf((g.z + R) / cw); cx1 = min(max(cx1, 0), GX - 1);
        int cy0 = (int)floorf((g.y - R) / ch); cy0 = min(max(cy0, 0), GY - 1);
        int cy1 = (int)floorf((g.w + R) / ch); cy1 = min(max(cy1, 0), GY - 1);
        int nr = 0, acc = 0;
        for (int cy = cy0; cy <= cy1; cy++) {
            int s0 = cellstart[cy * GX + cx0];
            int s1 = cellstart[cy * GX + cx1 + 1];
            s_seg[nr] = s0; s_pre[nr] = acc; acc += s1 - s0; nr++;
        }
        s_pre[nr] = acc;
        s_nrow = nr;
        s_redo = 0;
    }
    __syncthreads();
    int nr = s_nrow;
    int T = s_pre[nr];
    int lo = (T * wid) >> 2;
    int hi = (T * (wid + 1)) >> 2;

    unsigned long long kv[5]; float iv[5];
#pragma unroll
    for (int t = 0; t < 5; t++) { kv[t] = KMAX; iv[t] = 0.0f; }

    for (int v = lo + ln; v < hi; v += 64) {
        int rr = 0;
        while (s_pre[rr + 1] <= v) rr++;          // <= nr-1 iterations
        int s = s_seg[rr] + (v - s_pre[rr]);
        float4 p = pbs[s];
        bool o = (p.z > g.x) & (g.z > p.x) & (p.w > g.y) & (g.w > p.y);
        if (o) {
            int io = iorig[s];
            float cc, iou;
            cost_iou(p, pns[s], pis[s], g, cb, Gn, ga, clscol[io], cc, iou);
            ins5k(kv, packkey(cc, io)); ins5i(iv, iou);
        }
    }
    wavemerge5(kv, iv);

    if (ln == 0) {
#pragma unroll
        for (int t = 0; t < 5; t++) { s_k4[wid][t] = kv[t]; s_iv4[wid][t] = iv[t]; }
    }
    __syncthreads();

    unsigned long long mk0=KMAX, mk1=KMAX, mk2=KMAX, mk3=KMAX, mk4=KMAX;
    float mi0=-2.0f, mi1=-2.0f, mi2=-2.0f, mi3=-2.0f, mi4=-2.0f;
    if (tid == 0) {
        int h0 = 0, h1 = 0, h2 = 0, h3 = 0;
        unsigned long long mk[5];
#pragma unroll
        for (int r = 0; r < 5; r++) {
            unsigned long long v0 = (h0 < 5) ? s_k4[0][h0] : KMAX;
            unsigned long long v1 = (h1 < 5) ? s_k4[1][h1] : KMAX;
            unsigned long long v2 = (h2 < 5) ? s_k4[2][h2] : KMAX;
            unsigned long long v3 = (h3 < 5) ? s_k4[3][h3] : KMAX;
            unsigned long long best = v0; int sel = 0;
            if (v1 < best) { best = v1; sel = 1; }
            if (v2 < best) { best = v2; sel = 2; }
            if (v3 < best) { best = v3; sel = 3; }
            mk[r] = best;
            h0 += (sel == 0); h1 += (sel == 1); h2 += (sel == 2); h3 += (sel == 3);
        }
        int g0 = 0, g1 = 0, g2 = 0, g3 = 0;
        float mi[5];
#pragma unroll
        for (int r = 0; r < 5; r++) {
            float w0 = (g0 < 5) ? s_iv4[0][g0] : -2.0f;
            float w1 = (g1 < 5) ? s_iv4[1][g1] : -2.0f;
            float w2 = (g2 < 5) ? s_iv4[2][g2] : -2.0f;
            float w3 = (g3 < 5) ? s_iv4[3][g3] : -2.0f;
            float best = w0; int sel = 0;
            if (w1 > best) { best = w1; sel = 1; }
            if (w2 > best) { best = w2; sel = 2; }
            if (w3 > best) { best = w3; sel = 3; }
            mi[r] = best;
            g0 += (sel == 0); g1 += (sel == 1); g2 += (sel == 2); g3 += (sel == 3);
        }
        mk0 = mk[0]; mk1 = mk[1]; mk2 = mk[2]; mk3 = mk[3]; mk4 = mk[4];
        mi0 = mi[0]; mi1 = mi[1]; mi2 = mi[2]; mi3 = mi[3]; mi4 = mi[4];
        s_redo = (mk4 >= TKEY) ? 1 : 0;
    }
    __syncthreads();

    if (s_redo) {
#pragma unroll
        for (int t = 0; t < 5; t++) { kv[t] = KMAX; iv[t] = -1.0f; }
        for (int k = 0; k <= WMAIN; k++) {
            bool valid = (k < WMAIN) | (ln < WTAIL);
            if (valid) {
                int i = base_i + ln + k * 64;
                float cc, iou;
                cost_iou(pb4[i], pnorm[i], pinfo[i], g, cb, Gn, ga, clscol[i], cc, iou);
                ins5k(kv, packkey(cc, i)); ins5i(iv, iou);
            }
        }
        wavemerge5(kv, iv);
        if (ln == 0) {
#pragma unroll
            for (int t = 0; t < 5; t++) { s_k4[wid][t] = kv[t]; s_iv4[wid][t] = iv[t]; }
        }
        __syncthreads();
        if (tid == 0) {
            int h0 = 0, h1 = 0, h2 = 0, h3 = 0;
            unsigned long long mk[5];
#pragma unroll
            for (int r = 0; r < 5; r++) {
                unsigned long long v0 = (h0 < 5) ? s_k4[0][h0] : KMAX;
                unsigned long long v1 = (h1 < 5) ? s_k4[1][h1] : KMAX;
                unsigned long long v2 = (h2 < 5) ? s_k4[2][h2] : KMAX;
                unsigned long long v3 = (h3 < 5) ? s_k4[3][h3] : KMAX;
                unsigned long long best = v0; int sel = 0;
                if (v1 < best) { best = v1; sel = 1; }
                if (v2 < best) { best = v2; sel = 2; }
                if (v3 < best) { best = v3; sel = 3; }
                mk[r] = best;
                h0 += (sel == 0); h1 += (sel == 1); h2 += (sel == 2); h3 += (sel == 3);
            }
            int g0 = 0, g1 = 0, g2 = 0, g3 = 0;
            float mi[5];
#pragma unroll
            for (int r = 0; r < 5; r++) {
                float w0 = (g0 < 5) ? s_iv4[0][g0] : -2.0f;
                float w1 = (g1 < 5) ? s_iv4[1][g1] : -2.0f;
                float w2 = (g2 < 5) ? s_iv4[2][g2] : -2.0f;
                float w3 = (g3 < 5) ? s_iv4[3][g3] : -2.0f;
                float best = w0; int sel = 0;
                if (w1 > best) { best = w1; sel = 1; }
                if (w2 > best) { best = w2; sel = 2; }
                if (w3 > best) { best = w3; sel = 3; }
                mi[r] = best;
                g0 += (sel == 0); g1 += (sel == 1); g2 += (sel == 2); g3 += (sel == 3);
            }
            mk0 = mk[0]; mk1 = mk[1]; mk2 = mk[2]; mk3 = mk[3]; mk4 = mk[4];
            mi0 = mi[0]; mi1 = mi[1]; mi2 = mi[2]; mi3 = mi[3]; mi4 = mi[4];
        }
    }

    if (tid == 0) {
        float s = (((mi0 + mi1) + mi2) + mi3) + mi4;
        int dk = (int)s;                 // astype(int32): truncation
        if (dk < 1) dk = 1;
        dkarr[j] = dk;
        int b0 = keyidx(mk0), b1 = keyidx(mk1), b2 = keyidx(mk2);
        int b3 = keyidx(mk3), b4 = keyidx(mk4);
        top5[j * 5 + 0] = b0; top5[j * 5 + 1] = b1; top5[j * 5 + 2] = b2;
        top5[j * 5 + 3] = b3; top5[j * 5 + 4] = b4;
#pragma unroll
        for (int t = 0; t < 5; t++) {
            int r = (t == 0) ? b0 : (t == 1) ? b1 : (t == 2) ? b2
                  : (t == 3) ? b3 : b4;
            if (t < dk) {
                atomicAdd(&rowcnt[r], 1);
                atomicMin(&rowfirst[r], j);
                atomicMin(&rowiter[r], -1);   // initially matched
            }
        }
    }
}

// ---------------------------------------------------------------------------
// Fused prior-detect + pfix + surv (R10-R12, verbatim: rowcost caching).
// ---------------------------------------------------------------------------
__global__ __launch_bounds__(256) void k_pfixsurv(const float* __restrict__ pb,
        const float* __restrict__ gb, const int* __restrict__ glab,
        const float* __restrict__ clsval,
        const float4* __restrict__ pnorm, const float4* __restrict__ pinfo,
        const float4* __restrict__ gcb, const float4* __restrict__ gnm,
        const float* __restrict__ gar,
        int* __restrict__ prior, int* __restrict__ priorcol,
        int* __restrict__ colsum,
        const int* __restrict__ rowcnt, const int* __restrict__ top5,
        const int* __restrict__ dkarr,
        int* __restrict__ scal, int* __restrict__ priorslot,
        float* __restrict__ rowcost)
{
    int b = blockIdx.x;
    int tid = threadIdx.x;
    if (b >= 2500) {
        int j = (b - 2500) * 256 + tid;
        if (j >= NG) return;
        int c = 0;
        int dk = dkarr[j];
        for (int t = 0; t < dk; t++) if (rowcnt[top5[j * 5 + t]] == 1) c++;
        if (c) atomicAdd(&colsum[j], c);
        return;
    }
    __shared__ float rv[256]; __shared__ int ri[256];
    __shared__ int s_slot;
    for (int q = 0; q < 4; q++) {
        int row = b * 4 + q;
        if (rowcnt[row] <= 1) continue;      // uniform across block
        if (tid == 0) {
            prior[row] = 1;
            int s = atomicAdd(&scal[20], 1);
            int sl = (s < PSLOTS) ? s : -1;
            priorslot[row] = sl;
            s_slot = sl;
        }
        __syncthreads();
        int slot = s_slot;
        float* rc = (slot >= 0) ? (rowcost + (size_t)slot * NG) : nullptr;
        float4 p = ((const float4*)pb)[row];
        float4 pn = pnorm[row];
        float4 pi4 = pinfo[row];
        float best = FLT_MAX; int bj = 0x7fffffff;
        for (int j = tid; j < NG; j += 256) {
            float cc, iou;
            cost_iou(p, pn, pi4, ((const float4*)gb)[j], gcb[j], gnm[j], gar[j],
                     clsval[(size_t)glab[j] * NP + row], cc, iou);
            if (rc) rc[j] = cc;
            if (lexless(cc, j, best, bj)) { best = cc; bj = j; }
        }
        rv[tid] = best; ri[tid] = bj; __syncthreads();
        for (int w = 128; w > 0; w >>= 1) {
            if (tid < w) {
                float ov = rv[tid + w]; int oi = ri[tid + w];
                if (lexless(ov, oi, rv[tid], ri[tid])) { rv[tid] = ov; ri[tid] = oi; }
            }
            __syncthreads();
        }
        if (tid == 0) {
            priorcol[row] = ri[0];
            atomicAdd(&colsum[ri[0]], 1);
        }
        __syncthreads();
    }
}

// ---------------------------------------------------------------------------
// k_dyn v2: single-workgroup iteration fusion with ALL STATE IN LDS.
// R12 post-mortem: 45us at 0.02% VALU = pure global-latency chains + agent
// fences. Fix: rowcnt/rowiter/colsum/top5 live in LDS (118KB < 128KB proven
// static-LDS envelope on gfx950); rounds use LDS atomics + __syncthreads
// only (no threadfence in the loop). Global traffic kept: rowcost streaming
// (C), cost_iou tables (B fallback), fire-and-forget atomicMin(rowfirst) and
// priorcol writes (same-lane read-back each round -> program-order safe;
// one fence before the final read). Semantics identical to proven R10-R12
// (device atomics -> block-local LDS atomics, strictly stronger ordering).
// Nothing downstream reads rowcnt/rowiter/colsum after k_dyn -> no
// write-back; out computed from LDS state directly.
// ---------------------------------------------------------------------------
__global__ __launch_bounds__(1024) void k_dyn(
        const float* __restrict__ pb, const float* __restrict__ gb,
        const int* __restrict__ glab, const float* __restrict__ clsval,
        const float4* __restrict__ pnorm, const float4* __restrict__ pinfo,
        const float4* __restrict__ gcb, const float4* __restrict__ gnm,
        const float* __restrict__ gar,
        const int* __restrict__ top5, int* __restrict__ rowiter,
        int* __restrict__ rowcnt, int* __restrict__ rowfirst,
        int* __restrict__ colsum, const int* __restrict__ prior,
        int* __restrict__ priorcol, const int* __restrict__ priorslot,
        const float* __restrict__ rowcost, int* __restrict__ out)
{
    __shared__ int s_rowcnt[NP];      // 40 KB
    __shared__ int s_rowiter[NP];     // 40 KB
    __shared__ int s_top5[NG * 5];    // 20 KB
    __shared__ int s_plist[PCAP];     // 10.25 KB
    __shared__ int s_flist[FCAP];     // 4 KB
    __shared__ int s_colsum[NG];      // 4 KB
    __shared__ int s_pcnt;
    __shared__ int s_fcnt;
    __shared__ int s_body;
    __shared__ int s_multi;

    int tid = threadIdx.x;
    int wid = tid >> 6;
    int ln  = tid & 63;
    const float4* pb4 = (const float4*)pb;

    // ---- load state into LDS (coalesced) ----
    for (int i = tid; i < NP; i += 1024) {
        s_rowcnt[i] = rowcnt[i];
        s_rowiter[i] = rowiter[i];
    }
    for (int j = tid; j < NG; j += 1024) s_colsum[j] = colsum[j];
    for (int e = tid; e < NG * 5; e += 1024) s_top5[e] = top5[e];
    if (tid == 0) { s_pcnt = 0; s_multi = 0; }
    __syncthreads();
    for (int i = tid; i < NP; i += 1024) {
        if (prior[i]) {
            int s = atomicAdd(&s_pcnt, 1);
            if (s < PCAP) s_plist[s] = i;
        }
    }
    __syncthreads();
    int pcnt = (s_pcnt < PCAP) ? s_pcnt : PCAP;   // bound proof: <= 2500

    for (int t = 0; t < LMAX; t++) {
        if (tid == 0) { s_body = 0; s_fcnt = 0; }
        __syncthreads();

        // ---- B fast path: thread per column (all state LDS) ----
        for (int j = tid; j < NG; j += 1024) {
            if (s_colsum[j] != 0) continue;
            s_body = 1;                       // benign race (all write 1)
            int pos = -1;
            for (int r = 0; r < 5; r++) {
                int i = s_top5[j * 5 + r];
                if (s_rowiter[i] >= t) { pos = i; break; }
            }
            if (pos < 0) {
                int f = atomicAdd(&s_fcnt, 1);
                if (f < FCAP) s_flist[f] = j;   // FCAP >= NG: no overflow
                continue;
            }
            s_colsum[j] = 1;
            int old = atomicAdd(&s_rowcnt[pos], 1);
            if (old >= 1) s_multi = 1;
            atomicMin(&rowfirst[pos], j);       // global fire-and-forget
            atomicMin(&s_rowiter[pos], t);
        }
        __syncthreads();

        // ---- B fallback: wave per queued column (full uninflated argmin) ----
        int fcnt = (s_fcnt < FCAP) ? s_fcnt : FCAP;
        for (int q = wid; q < fcnt; q += 16) {
            int j = s_flist[q];
            float4 g  = ((const float4*)gb)[j];
            float4 cb = gcb[j];
            float4 Gn = gnm[j];
            float  ga = gar[j];
            const float* clscol = clsval + (size_t)glab[j] * NP;
            float best = FLT_MAX; int bi = 0x7fffffff;
            for (int i = ln; i < NP; i += 64) {
                if (s_rowiter[i] < t) continue;
                float cc, iou;
                cost_iou(pb4[i], pnorm[i], pinfo[i], g, cb, Gn, ga, clscol[i], cc, iou);
                if (lexless(cc, i, best, bi)) { best = cc; bi = i; }
            }
            wavered_lex(best, bi);
            if (ln == 0) {
                s_colsum[j] = 1;
                int old = atomicAdd(&s_rowcnt[bi], 1);
                if (old >= 1) s_multi = 1;
                atomicMin(&rowfirst[bi], j);
                atomicMin(&s_rowiter[bi], t);
            }
        }
        __syncthreads();

        if (!s_body) break;                  // reference while-cond fixpoint

        // ---- C (m_fix): wave per prior row, iff sticky multi ----
        if (s_multi) {
            for (int q = wid; q < pcnt; q += 16) {
                int row = s_plist[q];
                int k = t - s_rowiter[row]; if (k < 0) k = 0;  // prior: -1 -> t+1
                int slot = priorslot[row];
                float best = FLT_MAX; int bj = 0x7fffffff;
                if (slot >= 0) {
                    const float* rc = rowcost + (size_t)slot * NG;
                    for (int j = ln; j < NG; j += 64) {
                        float val = inflate(rc[j], k);
                        if (lexless(val, j, best, bj)) { best = val; bj = j; }
                    }
                } else {
                    float4 p = pb4[row];
                    float4 pn = pnorm[row];
                    float4 pi4 = pinfo[row];
                    for (int j = ln; j < NG; j += 64) {
                        float cc, iou;
                        cost_iou(p, pn, pi4, ((const float4*)gb)[j], gcb[j],
                                 gnm[j], gar[j],
                                 clsval[(size_t)glab[j] * NP + row], cc, iou);
                        float val = inflate(cc, k);
                        if (lexless(val, j, best, bj)) { best = val; bj = j; }
                    }
                }
                wavered_lex(best, bj);
                if (ln == 0) {
                    int nb = bj;
                    int oldc = priorcol[row];    // same lane wrote it (po-safe)
                    if (nb != oldc) {
                        atomicSub(&s_colsum[oldc], 1);
                        atomicAdd(&s_colsum[nb], 1);
                        priorcol[row] = nb;
                    }
                }
            }
        }
        __syncthreads();
    }

    // ---- final (folded): rowfirst/priorcol visibility fence, LDS rowcnt ----
    __threadfence();
    __syncthreads();
    for (int i = tid; i < NP; i += 1024) {
        int fg = s_rowcnt[i] > 0;
        out[i] = fg ? 1 : 0;
        out[NP + i] = fg ? (prior[i] ? priorcol[i] : rowfirst[i]) : 0;
    }
}

extern "C" void kernel_launch(void* const* d_in, const int* in_sizes, int n_in,
                              void* d_out, int out_size, void* d_ws, size_t ws_size,
                              hipStream_t stream)
{
    (void)in_sizes; (void)n_in; (void)out_size; (void)ws_size;
    const float* logits = (const float*)d_in[0];
    const float* pboxes = (const float*)d_in[1];
    const float* gboxes = (const float*)d_in[2];
    const int*   glab   = (const int*)d_in[3];
    const int*   imgh   = (const int*)d_in[4];
    const int*   imgw   = (const int*)d_in[5];
    int* out = (int*)d_out;

    char* w = (char*)d_ws;
    float*  clsval  = (float*)(w);                    // 3,200,000
    float4* pnorm   = (float4*)(w + 3200000);         //   160,000
    float4* pinfo   = (float4*)(w + 3360000);         //   160,000
    float4* gcb     = (float4*)(w + 3520000);         //    16,000
    float4* gnm     = (float4*)(w + 3536000);         //    16,000
    float*  gar     = (float*)(w + 3552000);          //     4,000
    int* rowcnt     = (int*)(w + 3556000);            //    40,000
    int* rowfirst   = (int*)(w + 3596000);            //    40,000
    int* rowiter    = (int*)(w + 3636000);            //    40,000
    int* prior      = (int*)(w + 3676000);            //    40,000
    int* priorcol   = (int*)(w + 3716000);            //    40,000
    int* top5       = (int*)(w + 3756000);            //    20,000
    int* dkarr      = (int*)(w + 3776000);            //     4,000
    int* colsum     = (int*)(w + 3780000);            //     4,000
    int* scal       = (int*)(w + 3784000);            //       128
    int* priorslot  = (int*)(w + 3784128);            //    40,000
    int* gorder     = (int*)(w + 3824128);            //     4,000
    float* rowcost  = (float*)(w + 3828128);          // 10,240,000 (2560x1000)
    float4* pbs     = (float4*)(w + 14068128);        //   160,000
    float4* pns     = (float4*)(w + 14228128);        //   160,000
    float4* pis     = (float4*)(w + 14388128);        //   160,000
    int* iorig      = (int*)(w + 14548128);           //    40,000
    int* cellstart  = (int*)(w + 14588128);           //     1,024 (161 used)
    float* gridp    = (float*)(w + 14589152);         //       128

    hipLaunchKernelGGL(k_prep, dim3(2703), dim3(256), 0, stream,
                       logits, pboxes, gboxes, glab, imgw, imgh,
                       clsval, pnorm, pinfo, gcb, gnm, gar,
                       rowcnt, rowfirst, rowiter, prior, priorcol, colsum, scal,
                       priorslot, gorder, iorig, cellstart, gridp);
    hipLaunchKernelGGL(k_sortcopy, dim3(40), dim3(256), 0, stream,
                       pboxes, pnorm, pinfo, iorig, pbs, pns, pis);
    hipLaunchKernelGGL(k_cost2, dim3(NG), dim3(256), 0, stream,
                       pboxes, gboxes, glab, clsval, pnorm, pinfo, gcb, gnm, gar,
                       gorder, pbs, pns, pis, iorig, cellstart, gridp,
                       rowcnt, rowfirst, rowiter, top5, dkarr);
    hipLaunchKernelGGL(k_pfixsurv, dim3(2504), dim3(256), 0, stream,
                       pboxes, gboxes, glab, clsval, pnorm, pinfo, gcb, gnm, gar,
                       prior, priorcol, colsum, rowcnt, top5, dkarr,
                       scal, priorslot, rowcost);
    hipLaunchKernelGGL(k_dyn, dim3(1), dim3(1024), 0, stream,
                       pboxes, gboxes, glab, clsval, pnorm, pinfo, gcb, gnm, gar,
                       top5, rowiter, rowcnt, rowfirst, colsum, prior,
                       priorcol, priorslot, rowcost, out);
}